// Round 9
// baseline (308.078 us; speedup 1.0000x reference)
//
#include <hip/hip_runtime.h>

typedef _Float16 f16;
typedef _Float16 f16x2 __attribute__((ext_vector_type(2)));
typedef _Float16 half8 __attribute__((ext_vector_type(8)));
typedef float f32x4 __attribute__((ext_vector_type(4)));

#define Hh 512
#define TT 256
#define VTOT 32000
#define S4H 100.0f  // i4 h quant scale

__device__ inline int dot8i4(int a, int b, int c) {
#if __has_builtin(__builtin_amdgcn_sdot8)
    return __builtin_amdgcn_sdot8(a, b, c, false);
#else
    int s = c;
#pragma unroll
    for (int i = 0; i < 8; ++i)
        s += ((a << (28 - 4 * i)) >> 28) * ((b << (28 - 4 * i)) >> 28);
    return s;
#endif
}

__device__ inline float tanh_fast(float x) {
    float ax = fabsf(x);
    float t = __expf(-2.f * ax);
    float th = (1.f - t) * __builtin_amdgcn_rcpf(1.f + t);
    return copysignf(th, x);
}

__device__ inline float block_sum(float v, float* red) {
#pragma unroll
    for (int o = 1; o < 64; o <<= 1) v += __shfl_xor(v, o);
    if ((threadIdx.x & 63) == 0) red[threadIdx.x >> 6] = v;
    __syncthreads();
    v = red[0] + red[1] + red[2] + red[3];
    __syncthreads();
    return v;
}

__device__ inline float block_max(float v, float* red) {
#pragma unroll
    for (int o = 1; o < 64; o <<= 1) v = fmaxf(v, __shfl_xor(v, o));
    if ((threadIdx.x & 63) == 0) red[threadIdx.x >> 6] = v;
    __syncthreads();
    v = fmaxf(fmaxf(red[0], red[1]), fmaxf(red[2], red[3]));
    __syncthreads();
    return v;
}

// ---- prep: emb gather+norm (b<512), h0 init (512,513), W_hh->i4 cvt (514..769).
// 256 thr.
__global__ void __launch_bounds__(256) k_prep(
    const int* __restrict__ src, const int* __restrict__ tgt,
    const float* __restrict__ encW, const float* __restrict__ decW,
    const float* __restrict__ eh0, const float* __restrict__ dh0,
    const float* __restrict__ encWhh, const float* __restrict__ decWhh,
    float* __restrict__ emb, float* __restrict__ h_seq, float* __restrict__ Hd,
    unsigned int* __restrict__ Wq, float* __restrict__ sWf) {
    const int b = blockIdx.x, tid = threadIdx.x;
    if (b >= 514) {  // W cvt: 4 rows per block, one row per wave
        const int bc = b - 514;
        const int R = bc * 4 + (tid >> 6);  // [0,1024)
        const int c = R >> 9, r = R & 511, j = tid & 63;
        const float* s = (c ? decWhh : encWhh) + (size_t)r * Hh + j * 8;
        float4 v0 = ((const float4*)s)[0];
        float4 v1 = ((const float4*)s)[1];
        float vv[8] = {v0.x, v0.y, v0.z, v0.w, v1.x, v1.y, v1.z, v1.w};
        float m = 0.f;
#pragma unroll
        for (int k = 0; k < 8; ++k) m = fmaxf(m, fabsf(vv[k]));
#pragma unroll
        for (int o = 1; o < 64; o <<= 1) m = fmaxf(m, __shfl_xor(m, o));
        m = fmaxf(m, 1e-30f);
        float qs = 7.f / m;
        unsigned int dw = 0;
#pragma unroll
        for (int k = 0; k < 8; ++k) {
            int q = (int)rintf(vv[k] * qs);
            dw |= ((unsigned int)(q & 0xF)) << (4 * k);
        }
        // row-resident layout: thread t=r reads uint4 u; dword j = u*4+dwi
        const int u = j >> 2, dwi = j & 3;
        Wq[((((size_t)(c * 16 + u)) * 512 + r) << 2) + dwi] = dw;
        if (j == 0) sWf[c * 512 + r] = m * (1.f / (7.f * S4H));
        return;
    }
    if (b >= 512) {  // h0 init
        const int c = b - 512;
        float2 v = ((const float2*)(c ? dh0 : eh0))[tid];
        if (c == 0)
            ((float2*)h_seq)[tid] = v;
        else
            ((float2*)Hd)[tid] = v;
        return;
    }
    const int c = b >> 8, t = b & 255;
    const int idx = c ? tgt[t] : src[t];
    const float* row = (c ? decW : encW) + (size_t)idx * Hh;
    float2 v = ((const float2*)row)[tid];
    __shared__ float red[4];
    float tot = block_sum(v.x * v.x + v.y * v.y, red);
    float inv = 1.f / fmaxf(sqrtf(tot), 1e-12f);
    float* orow = emb + ((size_t)c * TT + t) * Hh;
    float2 o;
    o.x = v.x * inv;
    o.y = v.y * inv;
    ((float2*)orow)[tid] = o;
}

// ---- P = emb @ W_hi^T + b. grid (64,2,2), 256 thr, 4 t per block, i-split by z.
__global__ void __launch_bounds__(256) k_proj(const float* __restrict__ emb,
                                              const float* __restrict__ eWhi,
                                              const float* __restrict__ eb,
                                              const float* __restrict__ dWhi,
                                              const float* __restrict__ db,
                                              float* __restrict__ P) {
    const int c = blockIdx.y, t0 = blockIdx.x * 4, tid = threadIdx.x;
    const int i = tid + blockIdx.z * 256;
    const float* Wv = c ? dWhi : eWhi;
    const float* b = c ? db : eb;
    __shared__ __align__(16) float esh[4][Hh];
#pragma unroll
    for (int rr = 0; rr < 4; ++rr) {
        ((float2*)esh[rr])[tid] =
            ((const float2*)(emb + ((size_t)c * TT + t0 + rr) * Hh))[tid];
    }
    __syncthreads();
    const float4* wp = (const float4*)(Wv + (size_t)i * Hh);
    float acc[4] = {0.f, 0.f, 0.f, 0.f};
    for (int j = 0; j < Hh / 4; ++j) {
        float4 w0 = wp[j];
#pragma unroll
        for (int rr = 0; rr < 4; ++rr) {
            float4 e = ((const float4*)esh[rr])[j];
            acc[rr] += w0.x * e.x + w0.y * e.y + w0.z * e.z + w0.w * e.w;
        }
    }
    float b0 = b[i];
#pragma unroll
    for (int rr = 0; rr < 4; ++rr)
        P[((size_t)c * TT + t0 + rr) * Hh + i] = acc[rr] + b0;
}

// ---- RNN chains, i4 dot8. grid 2, 512 thr (8 waves, 2/SIMD: latency hiding).
// Thread t owns row t (full 512 cols): W = 16 uint4 = 64 VGPR resident, pinned.
// h i4-packed (256B) in LDS; 16 wave-uniform b128 reads/thread/step.
// lgkm-only barrier (global stores float free). 1 barrier/step.
__global__ void __launch_bounds__(512, 2) k_chain(
    const uint4* __restrict__ Wq, const float* __restrict__ sWf,
    const float* __restrict__ P, const float* __restrict__ eh0,
    const float* __restrict__ dh0, float* __restrict__ h_seq,
    float* __restrict__ Hd) {
    const int c = blockIdx.x, t = threadIdx.x;
    __shared__ __align__(16) int hq[2][64];

    uint4 wq[16];
#pragma unroll
    for (int u = 0; u < 16; ++u) wq[u] = Wq[(size_t)(c * 16 + u) * 512 + t];
#pragma unroll
    for (int u = 0; u < 16; ++u)
        asm volatile("" : "+v"(wq[u].x), "+v"(wq[u].y), "+v"(wq[u].z),
                          "+v"(wq[u].w));
    const float frow = sWf[c * 512 + t];

    {
        float hv = (c ? dh0 : eh0)[t];
        int q = (int)rintf(fminf(fmaxf(hv * S4H, -7.f), 7.f));
        int b1 = (q & 0xF) | ((__shfl_down(q, 1) & 0xF) << 4);
        int b2 = (b1 & 0xFF) | ((__shfl_down(b1, 2) & 0xFF) << 8);
        int b4 = (b2 & 0xFFFF) | (__shfl_down(b2, 4) << 16);
        if ((t & 7) == 0) hq[0][t >> 3] = b4;
    }
    __syncthreads();

    const float* Pc = P + (size_t)c * TT * Hh;
    float pv = Pc[t];

    for (int step = 0; step < 256; ++step) {
        float pvn;
        if (step < 255) pvn = Pc[(size_t)(step + 1) * Hh + t];
        const uint4* hp = (const uint4*)hq[step & 1];
        int a0 = 0, a1 = 0;
#pragma unroll
        for (int u = 0; u < 16; ++u) {
            uint4 hv = hp[u];
            uint4 w0 = wq[u];
            a0 = dot8i4((int)w0.x, (int)hv.x, a0);
            a1 = dot8i4((int)w0.y, (int)hv.y, a1);
            a0 = dot8i4((int)w0.z, (int)hv.z, a0);
            a1 = dot8i4((int)w0.w, (int)hv.w, a1);
        }
        float hnew = tanh_fast((float)(a0 + a1) * frow + pv);
        pv = pvn;
        if (c == 0)
            h_seq[(size_t)(step + 1) * Hh + t] = hnew;
        else if (step < 255)
            Hd[(size_t)(step + 1) * Hh + t] = hnew;
        int q = (int)rintf(fminf(fmaxf(hnew * S4H, -7.f), 7.f));
        int b1 = (q & 0xF) | ((__shfl_down(q, 1) & 0xF) << 4);
        int b2 = (b1 & 0xFF) | ((__shfl_down(b1, 2) & 0xFF) << 8);
        int b4 = (b2 & 0xFFFF) | (__shfl_down(b2, 4) << 16);
        if ((t & 7) == 0) hq[(step + 1) & 1][t >> 3] = b4;
        asm volatile("s_waitcnt lgkmcnt(0)\ns_barrier" ::: "memory");
    }
}

// ---- attention scores + context for all t. grid 256, 256 thr. Writes CH=[c|h].
__global__ void __launch_bounds__(256) k_scores(const float* __restrict__ h_seq,
                                                const float* __restrict__ Hd,
                                                float* __restrict__ CH) {
    const int t = blockIdx.x, tid = threadIdx.x;
    __shared__ float h[Hh];
    __shared__ float w[257];
    __shared__ float red[4];
    ((float2*)h)[tid] = ((const float2*)(Hd + (size_t)t * Hh))[tid];
    __syncthreads();
    float sc0, sc1 = -3.0e38f;
    {
        const float4* row = (const float4*)(h_seq + (size_t)tid * Hh);
        float a = 0.f;
        for (int j = 0; j < Hh / 4; ++j) {
            float4 v = row[j];
            a += v.x * h[4 * j] + v.y * h[4 * j + 1] + v.z * h[4 * j + 2] +
                 v.w * h[4 * j + 3];
        }
        sc0 = a;
    }
    if (tid == 0) {
        const float4* row = (const float4*)(h_seq + (size_t)256 * Hh);
        float a = 0.f;
        for (int j = 0; j < Hh / 4; ++j) {
            float4 v = row[j];
            a += v.x * h[4 * j] + v.y * h[4 * j + 1] + v.z * h[4 * j + 2] +
                 v.w * h[4 * j + 3];
        }
        sc1 = a;
    }
    float m = block_max(fmaxf(sc0, sc1), red);
    float e0 = expf(sc0 - m);
    float e1 = (tid == 0) ? expf(sc1 - m) : 0.f;
    float tot = block_sum(e0 + e1, red);
    float inv = 1.f / tot;
    w[tid] = e0 * inv;
    if (tid == 0) w[256] = e1 * inv;
    __syncthreads();
    float* chrow = CH + (size_t)t * (2 * Hh);
    {
        const float2* hs2 = (const float2*)h_seq;  // [257][256] float2
        float2 a = {0.f, 0.f}, a2 = {0.f, 0.f};
        for (int s = 0; s < 256; s += 2) {
            float2 v0 = hs2[(size_t)s * 256 + tid];
            float2 v1 = hs2[(size_t)(s + 1) * 256 + tid];
            a.x += w[s] * v0.x;
            a.y += w[s] * v0.y;
            a2.x += w[s + 1] * v1.x;
            a2.y += w[s + 1] * v1.y;
        }
        float2 vl = hs2[(size_t)256 * 256 + tid];
        float2 o;
        o.x = a.x + a2.x + w[256] * vl.x;
        o.y = a.y + a2.y + w[256] * vl.y;
        ((float2*)chrow)[tid] = o;
    }
    ((float2*)(chrow + Hh))[tid] = ((const float2*)h)[tid];
}

// ---- Z = tanh(CH @ tnhW^T + b) as f16. grid (64,2), 256 thr, 4 t/block, i-split.
__global__ void __launch_bounds__(256) k_zgemm(const float* __restrict__ CH,
                                               const float* __restrict__ tnhW,
                                               const float* __restrict__ tnhb,
                                               f16* __restrict__ Zh) {
    const int t0 = blockIdx.x * 4, tid = threadIdx.x;
    const int i = tid + blockIdx.y * 256;
    __shared__ __align__(16) float chs[4][2 * Hh];
#pragma unroll
    for (int rr = 0; rr < 4; ++rr) {
        ((float4*)chs[rr])[tid] =
            ((const float4*)(CH + (size_t)(t0 + rr) * 2 * Hh))[tid];
    }
    __syncthreads();
    const float4* wp = (const float4*)(tnhW + (size_t)i * 2 * Hh);
    float acc[4] = {0.f, 0.f, 0.f, 0.f};
    for (int j = 0; j < 2 * Hh / 4; ++j) {
        float4 w0 = wp[j];
#pragma unroll
        for (int rr = 0; rr < 4; ++rr) {
            float4 e = ((const float4*)chs[rr])[j];
            acc[rr] += w0.x * e.x + w0.y * e.y + w0.z * e.z + w0.w * e.w;
        }
    }
    float b0 = tnhb[i];
#pragma unroll
    for (int rr = 0; rr < 4; ++rr)
        Zh[(size_t)(t0 + rr) * Hh + i] = (f16)tanhf(acc[rr] + b0);
}

// ---- logits via f16 MFMA + fused exp-sum. grid 500 (64 vocab rows), 256 thr.
__global__ void __launch_bounds__(256) k_logits(const f16* __restrict__ Zh,
                                                const float* __restrict__ outW,
                                                const int* __restrict__ tgt,
                                                float* __restrict__ denom,
                                                float* __restrict__ ltgt) {
    const int v0 = blockIdx.x * 64, tid = threadIdx.x;
    const int w = tid >> 6, l = tid & 63;
    const int l15 = l & 15, l4 = l >> 4;
    __shared__ __align__(16) f16 Wt[64][136];
    __shared__ __align__(16) f16 Zt[256][136];
    __shared__ float tsum[4][256];
    __shared__ int tgs[256];
    if (tid < 256) tgs[tid] = tgt[tid];

    f32x4 acc[16];
#pragma unroll
    for (int tt = 0; tt < 16; ++tt) acc[tt] = (f32x4){0.f, 0.f, 0.f, 0.f};

    for (int kc = 0; kc < 4; ++kc) {
        const int k0 = kc * 128;
#pragma unroll
        for (int p = 0; p < 8; ++p) {
            int g = p * 256 + tid;
            int row = g >> 5, f4 = g & 31;
            float4 v = *((const float4*)(outW + (size_t)(v0 + row) * Hh + k0 + f4 * 4));
            f16x2 lo = {(f16)v.x, (f16)v.y};
            f16x2 hi = {(f16)v.z, (f16)v.w};
            uint2 u;
            u.x = __builtin_bit_cast(unsigned, lo);
            u.y = __builtin_bit_cast(unsigned, hi);
            *((uint2*)&Wt[row][f4 * 4]) = u;
        }
#pragma unroll
        for (int p = 0; p < 16; ++p) {
            int g = p * 256 + tid;
            int row = g >> 4, u = g & 15;
            *((uint4*)&Zt[row][u * 8]) =
                *((const uint4*)(Zh + (size_t)row * Hh + k0 + u * 8));
        }
        __syncthreads();
        half8 a[4];
#pragma unroll
        for (int ks = 0; ks < 4; ++ks)
            a[ks] = *((const half8*)&Wt[w * 16 + l15][ks * 32 + l4 * 8]);
#pragma unroll
        for (int tt = 0; tt < 16; ++tt) {
#pragma unroll
            for (int ks = 0; ks < 4; ++ks) {
                half8 b = *((const half8*)&Zt[tt * 16 + l15][ks * 32 + l4 * 8]);
                acc[tt] = __builtin_amdgcn_mfma_f32_16x16x32_f16(a[ks], b, acc[tt],
                                                                 0, 0, 0);
            }
        }
        __syncthreads();
    }
    const int vbase = v0 + w * 16 + l4 * 4;
#pragma unroll
    for (int tt = 0; tt < 16; ++tt) {
        float e = __expf(acc[tt][0]) + __expf(acc[tt][1]) + __expf(acc[tt][2]) +
                  __expf(acc[tt][3]);
        e += __shfl_xor(e, 16);
        e += __shfl_xor(e, 32);
        if (l4 == 0) tsum[w][tt * 16 + l15] = e;
        int tglob = tt * 16 + l15;
        int rel = tgs[tglob] - vbase;
        if (rel >= 0 && rel < 4) {
            float val = (rel == 0) ? acc[tt][0]
                        : (rel == 1) ? acc[tt][1]
                        : (rel == 2) ? acc[tt][2]
                                     : acc[tt][3];
            ltgt[tglob] = val;
        }
    }
    __syncthreads();
    if (tid < 256) {
        float s = tsum[0][tid] + tsum[1][tid] + tsum[2][tid] + tsum[3][tid];
        atomicAdd(&denom[tid], s);
    }
}

// ---- final: mean over t of log(denom)-ltgt. grid 1, 256 thr
__global__ void k_final(const float* __restrict__ denom, const float* __restrict__ ltgt,
                        float* __restrict__ out) {
    const int t = threadIdx.x;
    float nll = logf(denom[t]) - ltgt[t];
    __shared__ float red[4];
    float v = nll;
#pragma unroll
    for (int o = 1; o < 64; o <<= 1) v += __shfl_xor(v, o);
    if ((t & 63) == 0) red[t >> 6] = v;
    __syncthreads();
    if (t == 0) out[0] = (red[0] + red[1] + red[2] + red[3]) * (1.f / 256.f);
}

extern "C" void kernel_launch(void* const* d_in, const int* in_sizes, int n_in,
                              void* d_out, int out_size, void* d_ws, size_t ws_size,
                              hipStream_t stream) {
    (void)in_sizes; (void)n_in; (void)out_size; (void)ws_size;
    const int* src = (const int*)d_in[0];
    const int* tgt = (const int*)d_in[1];
    const float* enc_emb = (const float*)d_in[2];
    const float* enc_h0 = (const float*)d_in[3];
    const float* enc_Whi = (const float*)d_in[4];
    const float* enc_Whh = (const float*)d_in[5];
    const float* enc_b = (const float*)d_in[6];
    const float* dec_emb = (const float*)d_in[7];
    const float* dec_h0 = (const float*)d_in[8];
    const float* dec_Whi = (const float*)d_in[9];
    const float* dec_Whh = (const float*)d_in[10];
    const float* dec_b = (const float*)d_in[11];
    const float* tnhW = (const float*)d_in[12];
    const float* tnhb = (const float*)d_in[13];
    const float* outW = (const float*)d_in[14];
    float* out = (float*)d_out;
    char* ws = (char*)d_ws;

    float* denom = (float*)ws;           // 256 f32
    float* ltgt = (float*)(ws + 1024);   // 256 f32
    size_t off = 4096;
    float* emb = (float*)(ws + off);    off += (size_t)2 * TT * Hh * 4;  // 1MB
    float* P = (float*)(ws + off);      off += (size_t)2 * TT * Hh * 4;  // 1MB
    float* h_seq = (float*)(ws + off);  off += (size_t)264 * Hh * 4;     // 528KB
    float* Hd = (float*)(ws + off);     off += (size_t)256 * Hh * 4;     // 512KB
    float* CH = (float*)(ws + off);     off += (size_t)TT * 2 * Hh * 4;  // 1MB
    f16* Zh = (f16*)(ws + off);         off += (size_t)TT * Hh * 2;      // 256KB
    uint4* Wq = (uint4*)(ws + off);     off += (size_t)2 * Hh * Hh;      // <=512KB
    float* sWf = (float*)(ws + off);    off += (size_t)2 * Hh * 4;       // 4KB

    hipMemsetAsync(ws, 0, 4096, stream);  // denom + ltgt
    k_prep<<<770, 256, 0, stream>>>(src, tgt, enc_emb, dec_emb, enc_h0, dec_h0,
                                    enc_Whh, dec_Whh, emb, h_seq, Hd,
                                    (unsigned int*)Wq, sWf);
    k_proj<<<dim3(64, 2, 2), 256, 0, stream>>>(emb, enc_Whi, enc_b, dec_Whi, dec_b, P);
    k_chain<<<2, 512, 0, stream>>>(Wq, sWf, P, enc_h0, dec_h0, h_seq, Hd);
    k_scores<<<256, 256, 0, stream>>>(h_seq, Hd, CH);
    k_zgemm<<<dim3(64, 2), 256, 0, stream>>>(CH, tnhW, tnhb, Zh);
    k_logits<<<500, 256, 0, stream>>>(Zh, outW, tgt, denom, ltgt);
    k_final<<<1, 256, 0, stream>>>(denom, ltgt, out);
}